// Round 20
// baseline (31.798 us; speedup 1.0000x reference)
//
#include <hip/hip_runtime.h>
#include <hip/hip_bf16.h>

#define S_LEN 2048

typedef __attribute__((ext_vector_type(8))) short bf16x8;
typedef __attribute__((ext_vector_type(4))) float f32x4;
typedef __attribute__((ext_vector_type(4))) unsigned int u32x4;

__device__ inline unsigned short f2b(float f) {
    unsigned u = __builtin_bit_cast(unsigned, f);
    return (unsigned short)((u + 0x7FFFu + ((u >> 16) & 1u)) >> 16);  // RNE
}

// XOR-swizzled byte offset in a [rows][64] bf16 LDS tile (T2).
__device__ inline int swoff(int row, int k) {
    int o = row * 128 + k * 2;
    return o ^ ((row & 7) << 4);
}

// ---------------------------------------------------------------------------
// K1 (prep4): 208 blocks, all resident (<=256 CUs) -> no deadlock.
//  b<8   : cantor table slice (fp32-faithful, exp via double), then RELEASE
//          one counting flag (count to 8).
//  b<72  : Wct = (W_in@W_out)^T bf16 via MFMA, 64x64 tiles (no wait).
//  b<80  : bc = b_in @ W_out + b_out (no wait).
//  b<208 : grouping+averaging: tid0 polls the cm flag with RELAXED RMW
//          (executes at LLC, no cache-invalidate storm — R10/R12 lesson),
//          one ACQUIRE load, then byte-identical scan/gather:
//          ballot+prefix = ascending j = lax.top_k stable tie-break; weights
//          exactly 1/n over first min(n,64) equal-cm j, 0 else (fp32 exp
//          underflow).
// Single-flag producer/consumer (NOT R12's full DAG: 1 wait, 8 producers,
// poll window ~1.5us hidden under the 72 Wct/bc blocks' compute).
// ---------------------------------------------------------------------------
__global__ __launch_bounds__(256) void prep4_kernel(
    const float* __restrict__ x,
    const float* __restrict__ W_in, const float* __restrict__ b_in,
    const float* __restrict__ W_out, const float* __restrict__ b_out,
    float* __restrict__ cmf, unsigned* __restrict__ flag,
    unsigned short* __restrict__ Wct, float* __restrict__ bc,
    unsigned short* __restrict__ xa) {
    __shared__ char lds[24576];
    const int b = blockIdx.x, tid = threadIdx.x;
    const int wid = tid >> 6, lane = tid & 63;
    const int l15 = lane & 15, l4 = lane >> 4;

    if (b < 8) {
        int s = b * 256 + tid;
        float pos = ((float)s + 0.5f) * (1.0f / 2048.0f);
        float cm = 0.0f, scale = 1.0f, lvlw = 1.0f;
        #pragma unroll
        for (int k = 1; k <= 5; ++k) {
            scale *= 3.0f; lvlw *= 0.5f;
            float y = fmodf(pos * scale, 3.0f);
            float d0 = y - 0.5f, d1 = y - 1.5f, d2 = y - 2.5f;
            float l0 = -(d0 * d0) * 4.0f;   // /(0.25+1e-10) == *4 in fp32
            float l1 = -(d1 * d1) * 4.0f;
            float l2 = -(d2 * d2) * 4.0f;
            float m = fmaxf(l0, fmaxf(l1, l2));
            float e0 = (float)exp((double)(l0 - m));
            float e1 = (float)exp((double)(l1 - m));
            float e2 = (float)exp((double)(l2 - m));
            float sum = (e0 + e1) + e2;
            float p1 = e1 / sum, p2 = e2 / sum;
            cm += (p2 + 0.5f * p1) * lvlw;
        }
        cmf[s] = cm;
        __syncthreads();
        if (tid == 0)
            __hip_atomic_fetch_add(flag, 1u, __ATOMIC_RELEASE,
                                   __HIP_MEMORY_SCOPE_AGENT);
    } else if (b < 72) {
        char* As = lds;            // [64][64] bf16 swizzled
        char* Bs = lds + 8192;
        int bb = b - 8, bm = bb >> 3, bn = bb & 7;
        int wr = wid >> 1, wc = wid & 1;
        int an = tid & 63, ajg = tid >> 6;        // A: row n, j-group of 16
        int bk = tid >> 2, bjq = (tid & 3) * 16;  // B: row k, j-quarter of 16
        const float* acol = W_out + bm * 64 + an;               // + j*512
        const float* brow = W_in + (size_t)(bn * 64 + bk) * 512 + bjq;
        f32x4 acc[2][2] = {};
        for (int k0 = 0; k0 < 512; k0 += 64) {
            unsigned short ta[16];
            #pragma unroll
            for (int i = 0; i < 16; ++i)
                ta[i] = f2b(acol[(size_t)(k0 + ajg * 16 + i) * 512]);
            *(u32x4*)(As + swoff(an, ajg * 16))     = *(u32x4*)&ta[0];
            *(u32x4*)(As + swoff(an, ajg * 16 + 8)) = *(u32x4*)&ta[8];
            unsigned short tb[16];
            #pragma unroll
            for (int i = 0; i < 4; ++i) {
                float4 v = *(const float4*)(brow + k0 + i * 4);
                tb[i*4+0] = f2b(v.x); tb[i*4+1] = f2b(v.y);
                tb[i*4+2] = f2b(v.z); tb[i*4+3] = f2b(v.w);
            }
            *(u32x4*)(Bs + swoff(bk, bjq))     = *(u32x4*)&tb[0];
            *(u32x4*)(Bs + swoff(bk, bjq + 8)) = *(u32x4*)&tb[8];
            __syncthreads();
            #pragma unroll
            for (int kk = 0; kk < 2; ++kk) {
                const int kb = kk * 32 + l4 * 8;
                bf16x8 af[2], bg[2];
                #pragma unroll
                for (int m = 0; m < 2; ++m)
                    af[m] = *(bf16x8*)(As + swoff(wr * 32 + m * 16 + l15, kb));
                #pragma unroll
                for (int n = 0; n < 2; ++n)
                    bg[n] = *(bf16x8*)(Bs + swoff(wc * 32 + n * 16 + l15, kb));
                #pragma unroll
                for (int m = 0; m < 2; ++m)
                    #pragma unroll
                    for (int n = 0; n < 2; ++n)
                        acc[m][n] = __builtin_amdgcn_mfma_f32_16x16x32_bf16(
                            af[m], bg[n], acc[m][n], 0, 0, 0);
            }
            __syncthreads();
        }
        #pragma unroll
        for (int m = 0; m < 2; ++m)
            #pragma unroll
            for (int r = 0; r < 4; ++r) {
                int row = bm * 64 + wr * 32 + m * 16 + l4 * 4 + r;
                #pragma unroll
                for (int n = 0; n < 2; ++n) {
                    int col = bn * 64 + wc * 32 + n * 16 + l15;
                    Wct[(size_t)row * 512 + col] = f2b(acc[m][n][r]);
                }
            }
    } else if (b < 80) {
        float (*red)[64] = (float(*)[64])lds;
        int nl = tid & 63, jc = tid >> 6;
        int n = (b - 72) * 64 + nl;
        float acc = 0.0f;
        #pragma unroll 8
        for (int j = jc * 128; j < jc * 128 + 128; ++j)
            acc += b_in[j] * W_out[(size_t)j * 512 + n];
        red[jc][nl] = acc;
        __syncthreads();
        if (jc == 0)
            bc[n] = b_out[n] + ((red[0][nl] + red[1][nl]) +
                                (red[2][nl] + red[3][nl]));
    } else {
        // wait for the cantor flag (8 producers), then proceed
        if (tid == 0) {
            while (__hip_atomic_fetch_add(flag, 0u, __ATOMIC_RELAXED,
                                          __HIP_MEMORY_SCOPE_AGENT) < 8u)
                __builtin_amdgcn_s_sleep(8);
            (void)__hip_atomic_load(flag, __ATOMIC_ACQUIRE,
                                    __HIP_MEMORY_SCOPE_AGENT);
        }
        __syncthreads();
        float* cml = (float*)lds;                       // 2048 f32 (8KB)
        int*   mem = (int*)(lds + 8192) + wid * 64;     // per-wave members
        for (int i = tid; i < 512; i += 256)
            *(float4*)&cml[i * 4] = *(const float4*)&cmf[i * 4];
        __syncthreads();
        int gbase = (b - 80) * 16 + wid * 4;            // 4 s per wave
        for (int q = 0; q < 4; ++q) {
            int s = gbase + q;
            float v = cml[s];
            int n = 0;
            for (int j0 = 0; j0 < S_LEN; j0 += 64) {
                float c = cml[j0 + lane];
                bool m = (c == v);
                unsigned long long mask = __ballot(m);
                if (m) {
                    int idx = n + __popcll(mask & ((1ull << lane) - 1ull));
                    if (idx < 64) mem[idx] = j0 + lane;
                }
                n += __popcll(mask);
            }
            int gn = n < 64 ? n : 64;
            float a0[8] = {}, a1[8] = {};
            for (int e = 0; e < gn; ++e) {
                int r = mem[e];
                const float* p0 = x + (size_t)r * 512 + lane * 8;
                const float* p1 = p0 + (size_t)S_LEN * 512;
                float4 u0 = *(const float4*)p0, u1 = *(const float4*)(p0 + 4);
                float4 w0 = *(const float4*)p1, w1 = *(const float4*)(p1 + 4);
                a0[0] += u0.x; a0[1] += u0.y; a0[2] += u0.z; a0[3] += u0.w;
                a0[4] += u1.x; a0[5] += u1.y; a0[6] += u1.z; a0[7] += u1.w;
                a1[0] += w0.x; a1[1] += w0.y; a1[2] += w0.z; a1[3] += w0.w;
                a1[4] += w1.x; a1[5] += w1.y; a1[6] += w1.z; a1[7] += w1.w;
            }
            float gi = 1.0f / (float)gn;
            unsigned short t0[8], t1[8];
            #pragma unroll
            for (int i = 0; i < 8; ++i) {
                t0[i] = f2b(a0[i] * gi);
                t1[i] = f2b(a1[i] * gi);
            }
            *(u32x4*)(xa + (size_t)s * 512 + lane * 8)           = *(u32x4*)t0;
            *(u32x4*)(xa + (size_t)(S_LEN + s) * 512 + lane * 8) = *(u32x4*)t1;
        }
    }
}

// ---------------------------------------------------------------------------
// K2 (byte-identical to R19): out = x + xa @ Wct^T + bc.  BM=32 x BN=64,
// BK=64, single-buffer 12KB LDS, 1024 blocks = 4 blocks/CU, XCD-chunked.
// ---------------------------------------------------------------------------
__global__ __launch_bounds__(256, 4) void gemmF_kernel(
    const float* __restrict__ x, const unsigned short* __restrict__ xa,
    const unsigned short* __restrict__ Wct, const float* __restrict__ bc,
    float* __restrict__ out) {
    __shared__ char lds[12288];             // As 4KB | Bs 8KB
    char* As = lds;
    char* Bs = lds + 4096;
    const int tid = threadIdx.x;
    const int id = blockIdx.x;              // 0..1023
    const int xcd = id & 7, slot = id >> 3; // slot 0..127
    const int bm = xcd * 16 + (slot & 15);  // 0..127 (32-row panels)
    const int bn = slot >> 4;               // 0..7   (64-col panels)
    const int wid = tid >> 6, lane = tid & 63;
    const int wr = wid >> 1, wc = wid & 1;
    const int l15 = lane & 15, l4 = lane >> 4;
    const int arow = tid >> 3, akq = (tid & 7) * 8;    // A: 32 rows x 8 elems
    const int brow = tid >> 2, bkq = (tid & 3) * 16;   // B: 64 rows x 16 elems

    const unsigned short* asrc = xa  + (size_t)(bm * 32 + arow) * 512 + akq;
    const unsigned short* bsrc = Wct + (size_t)(bn * 64 + brow) * 512 + bkq;

    u32x4 arg, brg[2];
    auto la = [&](int k0) { arg = *(const u32x4*)(asrc + k0); };
    auto lb = [&](int k0) {
        brg[0] = *(const u32x4*)(bsrc + k0);
        brg[1] = *(const u32x4*)(bsrc + k0 + 8);
    };
    auto st = [&]() {
        *(u32x4*)(As + swoff(arow, akq))     = arg;
        *(u32x4*)(Bs + swoff(brow, bkq))     = brg[0];
        *(u32x4*)(Bs + swoff(brow, bkq + 8)) = brg[1];
    };

    f32x4 acc[2] = {};
    la(0); lb(0);
    for (int t = 0; t < 8; ++t) {
        st();
        __syncthreads();
        if (t < 7) { la((t + 1) * 64); lb((t + 1) * 64); }
        #pragma unroll
        for (int kk = 0; kk < 2; ++kk) {
            const int kb = kk * 32 + l4 * 8;
            bf16x8 af = *(bf16x8*)(As + swoff(wr * 16 + l15, kb));
            bf16x8 bg[2];
            #pragma unroll
            for (int n = 0; n < 2; ++n)
                bg[n] = *(bf16x8*)(Bs + swoff(wc * 32 + n * 16 + l15, kb));
            #pragma unroll
            for (int n = 0; n < 2; ++n)
                acc[n] = __builtin_amdgcn_mfma_f32_16x16x32_bf16(
                    af, bg[n], acc[n], 0, 0, 0);
        }
        __syncthreads();
    }

    float bv[2];
    #pragma unroll
    for (int n = 0; n < 2; ++n) bv[n] = bc[bn * 64 + wc * 32 + n * 16 + l15];
    #pragma unroll
    for (int r = 0; r < 4; ++r) {
        int row = bm * 32 + wr * 16 + l4 * 4 + r;
        #pragma unroll
        for (int n = 0; n < 2; ++n) {
            int col = bn * 64 + wc * 32 + n * 16 + l15;
            float v = acc[n][r] + bv[n];
            out[(size_t)row * 512 + col] = x[(size_t)row * 512 + col] + v;
        }
    }
}

extern "C" void kernel_launch(void* const* d_in, const int* in_sizes, int n_in,
                              void* d_out, int out_size, void* d_ws, size_t ws_size,
                              hipStream_t stream) {
    const float* x     = (const float*)d_in[0];
    const float* W_in  = (const float*)d_in[1];
    const float* b_in  = (const float*)d_in[2];
    const float* W_out = (const float*)d_in[3];
    const float* b_out = (const float*)d_in[4];
    float* out = (float*)d_out;

    char* ws = (char*)d_ws;
    unsigned short* Wct  = (unsigned short*)ws;                          // 512 KB
    float*          bc   = (float*)(ws + 524288);                        // 4 KB pad
    float*          cmf  = (float*)(ws + 524288 + 4096);                 // 8 KB
    unsigned short* xa   = (unsigned short*)(ws + 524288 + 4096 + 8192); // 4 MB
    unsigned*       flag = (unsigned*)(ws + 524288 + 4096 + 8192 + 4194304);

    hipMemsetAsync(flag, 0, 64, stream);
    prep4_kernel<<<208, 256, 0, stream>>>(x, W_in, b_in, W_out, b_out,
                                          cmf, flag, Wct, bc, xa);
    gemmF_kernel<<<1024, 256, 0, stream>>>(x, xa, Wct, bc, out);
}

// Round 21
// 29.007 us; speedup vs baseline: 1.0962x; 1.0962x over previous
//
#include <hip/hip_runtime.h>
#include <hip/hip_bf16.h>

#define S_LEN 2048

typedef __attribute__((ext_vector_type(8))) short bf16x8;
typedef __attribute__((ext_vector_type(4))) float f32x4;
typedef __attribute__((ext_vector_type(4))) unsigned int u32x4;

__device__ inline unsigned short f2b(float f) {
    unsigned u = __builtin_bit_cast(unsigned, f);
    return (unsigned short)((u + 0x7FFFu + ((u >> 16) & 1u)) >> 16);  // RNE
}

// XOR-swizzled byte offset in a [rows][64] bf16 LDS tile (T2).
__device__ inline int swoff(int row, int k) {
    int o = row * 128 + k * 2;
    return o ^ ((row & 7) << 4);
}

// ---------------------------------------------------------------------------
// K0: cantor table, computed once. fp32-faithful; exp via double.
// ---------------------------------------------------------------------------
__global__ __launch_bounds__(256) void cantor_kernel(float* __restrict__ cmf) {
    int s = blockIdx.x * 256 + threadIdx.x;
    float pos = ((float)s + 0.5f) * (1.0f / 2048.0f);
    float cm = 0.0f, scale = 1.0f, lvlw = 1.0f;
    #pragma unroll
    for (int k = 1; k <= 5; ++k) {
        scale *= 3.0f; lvlw *= 0.5f;
        float y = fmodf(pos * scale, 3.0f);
        float d0 = y - 0.5f, d1 = y - 1.5f, d2 = y - 2.5f;
        float l0 = -(d0 * d0) * 4.0f;   // /(0.25+1e-10) == *4 in fp32
        float l1 = -(d1 * d1) * 4.0f;
        float l2 = -(d2 * d2) * 4.0f;
        float m = fmaxf(l0, fmaxf(l1, l2));
        float e0 = (float)exp((double)(l0 - m));
        float e1 = (float)exp((double)(l1 - m));
        float e2 = (float)exp((double)(l2 - m));
        float sum = (e0 + e1) + e2;
        float p1 = e1 / sum, p2 = e2 / sum;
        cm += (p2 + 0.5f * p1) * lvlw;
    }
    cmf[s] = cm;
}

// ---------------------------------------------------------------------------
// K1: 200 blocks.
//  b<64  : Wct = (W_in@W_out)^T bf16 via MFMA, 64x64 tiles.
//  b<72  : bc = b_in @ W_out + b_out.
//  b<200 : grouping+averaging, 128 blocks x 16 s. cmf loaded from global;
//          ballot+prefix = ascending j = lax.top_k stable tie-break; weights
//          exactly 1/n over first min(n,64) equal-cm j, 0 else by fp32 exp
//          underflow.
// ---------------------------------------------------------------------------
__global__ __launch_bounds__(256) void prep3_kernel(
    const float* __restrict__ x,
    const float* __restrict__ W_in, const float* __restrict__ b_in,
    const float* __restrict__ W_out, const float* __restrict__ b_out,
    const float* __restrict__ cmf,
    unsigned short* __restrict__ Wct, float* __restrict__ bc,
    unsigned short* __restrict__ xa) {
    __shared__ char lds[24576];
    const int b = blockIdx.x, tid = threadIdx.x;
    const int wid = tid >> 6, lane = tid & 63;
    const int l15 = lane & 15, l4 = lane >> 4;

    if (b < 64) {
        char* As = lds;            // [64][64] bf16 swizzled
        char* Bs = lds + 8192;
        int bm = b >> 3, bn = b & 7;
        int wr = wid >> 1, wc = wid & 1;
        int an = tid & 63, ajg = tid >> 6;        // A: row n, j-group of 16
        int bk = tid >> 2, bjq = (tid & 3) * 16;  // B: row k, j-quarter of 16
        const float* acol = W_out + bm * 64 + an;               // + j*512
        const float* brow = W_in + (size_t)(bn * 64 + bk) * 512 + bjq;
        f32x4 acc[2][2] = {};
        for (int k0 = 0; k0 < 512; k0 += 64) {
            unsigned short ta[16];
            #pragma unroll
            for (int i = 0; i < 16; ++i)
                ta[i] = f2b(acol[(size_t)(k0 + ajg * 16 + i) * 512]);
            *(u32x4*)(As + swoff(an, ajg * 16))     = *(u32x4*)&ta[0];
            *(u32x4*)(As + swoff(an, ajg * 16 + 8)) = *(u32x4*)&ta[8];
            unsigned short tb[16];
            #pragma unroll
            for (int i = 0; i < 4; ++i) {
                float4 v = *(const float4*)(brow + k0 + i * 4);
                tb[i*4+0] = f2b(v.x); tb[i*4+1] = f2b(v.y);
                tb[i*4+2] = f2b(v.z); tb[i*4+3] = f2b(v.w);
            }
            *(u32x4*)(Bs + swoff(bk, bjq))     = *(u32x4*)&tb[0];
            *(u32x4*)(Bs + swoff(bk, bjq + 8)) = *(u32x4*)&tb[8];
            __syncthreads();
            #pragma unroll
            for (int kk = 0; kk < 2; ++kk) {
                const int kb = kk * 32 + l4 * 8;
                bf16x8 af[2], bg[2];
                #pragma unroll
                for (int m = 0; m < 2; ++m)
                    af[m] = *(bf16x8*)(As + swoff(wr * 32 + m * 16 + l15, kb));
                #pragma unroll
                for (int n = 0; n < 2; ++n)
                    bg[n] = *(bf16x8*)(Bs + swoff(wc * 32 + n * 16 + l15, kb));
                #pragma unroll
                for (int m = 0; m < 2; ++m)
                    #pragma unroll
                    for (int n = 0; n < 2; ++n)
                        acc[m][n] = __builtin_amdgcn_mfma_f32_16x16x32_bf16(
                            af[m], bg[n], acc[m][n], 0, 0, 0);
            }
            __syncthreads();
        }
        #pragma unroll
        for (int m = 0; m < 2; ++m)
            #pragma unroll
            for (int r = 0; r < 4; ++r) {
                int row = bm * 64 + wr * 32 + m * 16 + l4 * 4 + r;
                #pragma unroll
                for (int n = 0; n < 2; ++n) {
                    int col = bn * 64 + wc * 32 + n * 16 + l15;
                    Wct[(size_t)row * 512 + col] = f2b(acc[m][n][r]);
                }
            }
    } else if (b < 72) {
        float (*red)[64] = (float(*)[64])lds;
        int nl = tid & 63, jc = tid >> 6;
        int n = (b - 64) * 64 + nl;
        float acc = 0.0f;
        #pragma unroll 8
        for (int j = jc * 128; j < jc * 128 + 128; ++j)
            acc += b_in[j] * W_out[(size_t)j * 512 + n];
        red[jc][nl] = acc;
        __syncthreads();
        if (jc == 0)
            bc[n] = b_out[n] + ((red[0][nl] + red[1][nl]) +
                                (red[2][nl] + red[3][nl]));
    } else {
        float* cml = (float*)lds;                       // 2048 f32 (8KB)
        int*   mem = (int*)(lds + 8192) + wid * 64;     // per-wave members
        for (int i = tid; i < 512; i += 256)
            *(float4*)&cml[i * 4] = *(const float4*)&cmf[i * 4];
        __syncthreads();
        int gbase = (b - 72) * 16 + wid * 4;            // 4 s per wave
        for (int q = 0; q < 4; ++q) {
            int s = gbase + q;
            float v = cml[s];
            int n = 0;
            for (int j0 = 0; j0 < S_LEN; j0 += 64) {
                float c = cml[j0 + lane];
                bool m = (c == v);
                unsigned long long mask = __ballot(m);
                if (m) {
                    int idx = n + __popcll(mask & ((1ull << lane) - 1ull));
                    if (idx < 64) mem[idx] = j0 + lane;
                }
                n += __popcll(mask);
            }
            int gn = n < 64 ? n : 64;
            float a0[8] = {}, a1[8] = {};
            for (int e = 0; e < gn; ++e) {
                int r = mem[e];
                const float* p0 = x + (size_t)r * 512 + lane * 8;
                const float* p1 = p0 + (size_t)S_LEN * 512;
                float4 u0 = *(const float4*)p0, u1 = *(const float4*)(p0 + 4);
                float4 w0 = *(const float4*)p1, w1 = *(const float4*)(p1 + 4);
                a0[0] += u0.x; a0[1] += u0.y; a0[2] += u0.z; a0[3] += u0.w;
                a0[4] += u1.x; a0[5] += u1.y; a0[6] += u1.z; a0[7] += u1.w;
                a1[0] += w0.x; a1[1] += w0.y; a1[2] += w0.z; a1[3] += w0.w;
                a1[4] += w1.x; a1[5] += w1.y; a1[6] += w1.z; a1[7] += w1.w;
            }
            float gi = 1.0f / (float)gn;
            unsigned short t0[8], t1[8];
            #pragma unroll
            for (int i = 0; i < 8; ++i) {
                t0[i] = f2b(a0[i] * gi);
                t1[i] = f2b(a1[i] * gi);
            }
            *(u32x4*)(xa + (size_t)s * 512 + lane * 8)           = *(u32x4*)t0;
            *(u32x4*)(xa + (size_t)(S_LEN + s) * 512 + lane * 8) = *(u32x4*)t1;
        }
    }
}

// ---------------------------------------------------------------------------
// K2: out = x + xa @ Wct^T + bc.  BM=32 x BN=64, BK=64, single-buffer
// 12KB LDS, 1024 blocks = 4 blocks/CU, XCD-chunked swizzle.
// ---------------------------------------------------------------------------
__global__ __launch_bounds__(256, 4) void gemmF_kernel(
    const float* __restrict__ x, const unsigned short* __restrict__ xa,
    const unsigned short* __restrict__ Wct, const float* __restrict__ bc,
    float* __restrict__ out) {
    __shared__ char lds[12288];             // As 4KB | Bs 8KB
    char* As = lds;
    char* Bs = lds + 4096;
    const int tid = threadIdx.x;
    const int id = blockIdx.x;              // 0..1023
    const int xcd = id & 7, slot = id >> 3; // slot 0..127
    const int bm = xcd * 16 + (slot & 15);  // 0..127 (32-row panels)
    const int bn = slot >> 4;               // 0..7   (64-col panels)
    const int wid = tid >> 6, lane = tid & 63;
    const int wr = wid >> 1, wc = wid & 1;
    const int l15 = lane & 15, l4 = lane >> 4;
    const int arow = tid >> 3, akq = (tid & 7) * 8;    // A: 32 rows x 8 elems
    const int brow = tid >> 2, bkq = (tid & 3) * 16;   // B: 64 rows x 16 elems

    const unsigned short* asrc = xa  + (size_t)(bm * 32 + arow) * 512 + akq;
    const unsigned short* bsrc = Wct + (size_t)(bn * 64 + brow) * 512 + bkq;

    u32x4 arg, brg[2];
    auto la = [&](int k0) { arg = *(const u32x4*)(asrc + k0); };
    auto lb = [&](int k0) {
        brg[0] = *(const u32x4*)(bsrc + k0);
        brg[1] = *(const u32x4*)(bsrc + k0 + 8);
    };
    auto st = [&]() {
        *(u32x4*)(As + swoff(arow, akq))     = arg;
        *(u32x4*)(Bs + swoff(brow, bkq))     = brg[0];
        *(u32x4*)(Bs + swoff(brow, bkq + 8)) = brg[1];
    };

    f32x4 acc[2] = {};
    la(0); lb(0);
    for (int t = 0; t < 8; ++t) {
        st();
        __syncthreads();
        if (t < 7) { la((t + 1) * 64); lb((t + 1) * 64); }
        #pragma unroll
        for (int kk = 0; kk < 2; ++kk) {
            const int kb = kk * 32 + l4 * 8;
            bf16x8 af = *(bf16x8*)(As + swoff(wr * 16 + l15, kb));
            bf16x8 bg[2];
            #pragma unroll
            for (int n = 0; n < 2; ++n)
                bg[n] = *(bf16x8*)(Bs + swoff(wc * 32 + n * 16 + l15, kb));
            #pragma unroll
            for (int n = 0; n < 2; ++n)
                acc[n] = __builtin_amdgcn_mfma_f32_16x16x32_bf16(
                    af, bg[n], acc[n], 0, 0, 0);
        }
        __syncthreads();
    }

    float bv[2];
    #pragma unroll
    for (int n = 0; n < 2; ++n) bv[n] = bc[bn * 64 + wc * 32 + n * 16 + l15];
    #pragma unroll
    for (int r = 0; r < 4; ++r) {
        int row = bm * 32 + wr * 16 + l4 * 4 + r;
        #pragma unroll
        for (int n = 0; n < 2; ++n) {
            int col = bn * 64 + wc * 32 + n * 16 + l15;
            float v = acc[n][r] + bv[n];
            out[(size_t)row * 512 + col] = x[(size_t)row * 512 + col] + v;
        }
    }
}

extern "C" void kernel_launch(void* const* d_in, const int* in_sizes, int n_in,
                              void* d_out, int out_size, void* d_ws, size_t ws_size,
                              hipStream_t stream) {
    const float* x     = (const float*)d_in[0];
    const float* W_in  = (const float*)d_in[1];
    const float* b_in  = (const float*)d_in[2];
    const float* W_out = (const float*)d_in[3];
    const float* b_out = (const float*)d_in[4];
    float* out = (float*)d_out;

    char* ws = (char*)d_ws;
    unsigned short* Wct = (unsigned short*)ws;                     // 512 KB
    float*          bc  = (float*)(ws + 524288);                   // 2 KB
    float*          cmf = (float*)(ws + 524288 + 4096);            // 8 KB
    unsigned short* xa  = (unsigned short*)(ws + 524288 + 4096 + 8192); // 4 MB

    cantor_kernel<<<8, 256, 0, stream>>>(cmf);
    prep3_kernel<<<200, 256, 0, stream>>>(x, W_in, b_in, W_out, b_out,
                                          cmf, Wct, bc, xa);
    gemmF_kernel<<<1024, 256, 0, stream>>>(x, xa, Wct, bc, out);
}